// Round 1
// baseline (92.372 us; speedup 1.0000x reference)
//
#include <hip/hip_runtime.h>
#include <math.h>

#define B 64
#define K 16
#define J 512
#define I 128

__device__ __constant__ float kSCALE = 0.08838834764831845f; // 1/sqrt(128)
#define EPSF 1e-20f

// ---------------------------------------------------------------------------
// K1: c_raw[k][j][b] = SCALE * sum_i (x[b,j,i]*w[k,j,i])^2
//     = SCALE * sum_i x^2 * w^2
// One wave per (b,j); lanes cover i (2 floats each); loop over k in registers.
// ---------------------------------------------------------------------------
__global__ __launch_bounds__(256) void k1_craw(const float* __restrict__ x,
                                               const float* __restrict__ w,
                                               float* __restrict__ cw) {
    int gtid = blockIdx.x * 256 + threadIdx.x;
    int wave = gtid >> 6;          // 0 .. B*J-1
    int lane = threadIdx.x & 63;
    int b = wave / J;
    int j = wave - b * J;

    const float2 xv = *(const float2*)(x + ((size_t)b * J + j) * I + lane * 2);
    float xx0 = xv.x * xv.x;
    float xx1 = xv.y * xv.y;

#pragma unroll
    for (int k = 0; k < K; ++k) {
        const float2 wv = *(const float2*)(w + ((size_t)k * J + j) * I + lane * 2);
        float p = xx0 * wv.x * wv.x + xx1 * wv.y * wv.y;
#pragma unroll
        for (int m = 32; m >= 1; m >>= 1) p += __shfl_xor(p, m, 64);
        if (lane == 0) cw[((size_t)k * J + j) * B + b] = p * kSCALE;
    }
}

// ---------------------------------------------------------------------------
// K2: softmax over batch dim (64 values) per (k,j), + bias. In-place on cw.
// One wave per (k,j); lane = b. Fully coalesced thanks to [k][j][b] layout.
// ---------------------------------------------------------------------------
__global__ __launch_bounds__(256) void k2_softmax(float* __restrict__ cw,
                                                  const float* __restrict__ bias) {
    int gtid = blockIdx.x * 256 + threadIdx.x;
    int kj = gtid >> 6;            // 0 .. K*J-1
    int lane = threadIdx.x & 63;   // = b

    float v = cw[(size_t)kj * B + lane];
    float m = v;
#pragma unroll
    for (int s = 32; s >= 1; s >>= 1) m = fmaxf(m, __shfl_xor(m, s, 64));
    float e = expf(v - m);
    float ssum = e;
#pragma unroll
    for (int s = 32; s >= 1; s >>= 1) ssum += __shfl_xor(ssum, s, 64);
    cw[(size_t)kj * B + lane] = e / ssum + bias[kj];
}

// ---------------------------------------------------------------------------
// K3: partial weighted sums over j:
//   sp[p][b][k][i] = sum_{j in chunk} x[b,j,i]*w[k,j,i]*c[b,k,j]
// Block: (j-half, b-pair, k-pair); 256 threads = (jj in 0..1) x (i in 0..127).
// 2x2 register tile amortizes x/w reads. XCD-swizzled block ids keep each
// XCD's x/w working set in its private L2.
// ---------------------------------------------------------------------------
__global__ __launch_bounds__(256) void k3_wsum(const float* __restrict__ x,
                                               const float* __restrict__ w,
                                               const float* __restrict__ cw,
                                               float* __restrict__ sp) {
    int raw = blockIdx.x;                 // 0..511, 512 % 8 == 0
    int swz = (raw & 7) * 64 + (raw >> 3);
    int jh = swz >> 8;                    // 0..1 (j half)
    int bp = (swz >> 3) & 31;             // b pair 0..31
    int kp = swz & 7;                     // k pair 0..7

    int jj = threadIdx.x >> 7;            // 0..1
    int i  = threadIdx.x & 127;

    int b0 = bp * 2;
    int k0 = kp * 2;

    float a00 = 0.f, a01 = 0.f, a10 = 0.f, a11 = 0.f;

    int jbeg = jh * 256 + jj;
    int jend = jh * 256 + 256;
    for (int j = jbeg; j < jend; j += 2) {
        float xa = x[((size_t)b0 * J + j) * I + i];
        float xb = x[((size_t)(b0 + 1) * J + j) * I + i];
        float wa = w[((size_t)k0 * J + j) * I + i];
        float wb = w[((size_t)(k0 + 1) * J + j) * I + i];
        float c00 = cw[((size_t)k0 * J + j) * B + b0];
        float c01 = cw[((size_t)k0 * J + j) * B + b0 + 1];
        float c10 = cw[((size_t)(k0 + 1) * J + j) * B + b0];
        float c11 = cw[((size_t)(k0 + 1) * J + j) * B + b0 + 1];
        a00 += xa * wa * c00;
        a01 += xa * wb * c10;
        a10 += xb * wa * c01;
        a11 += xb * wb * c11;
    }

    int p = jh * 2 + jj;                  // 0..3
    size_t base = (((size_t)p * B + b0) * K + k0) * I + i;
    sp[base]                 = a00;       // [p][b0  ][k0  ][i]
    sp[base + I]             = a01;       // [p][b0  ][k0+1][i]
    sp[base + (size_t)K * I] = a10;       // [p][b0+1][k0  ][i]
    sp[base + (size_t)(K + 1) * I] = a11; // [p][b0+1][k0+1][i]
}

// ---------------------------------------------------------------------------
// K4: s = sum of 4 partials; squash over i; write out[b,k,i].
// One block (128 threads) per (b,k).
// ---------------------------------------------------------------------------
__global__ __launch_bounds__(128) void k4_squash(const float* __restrict__ sp,
                                                 float* __restrict__ out) {
    int bk = blockIdx.x;                  // 0 .. B*K-1
    int i = threadIdx.x;                  // 0..127
    const size_t stride = (size_t)B * K * I;
    size_t base = (size_t)bk * I + i;

    float s = sp[base] + sp[base + stride] + sp[base + 2 * stride] +
              sp[base + 3 * stride];

    float q = s * s;
#pragma unroll
    for (int m = 32; m >= 1; m >>= 1) q += __shfl_xor(q, m, 64);

    __shared__ float red[2];
    if ((threadIdx.x & 63) == 0) red[threadIdx.x >> 6] = q;
    __syncthreads();
    float nsq = red[0] + red[1];

    float n = sqrtf(nsq);
    float factor = (1.0f - 1.0f / (expf(n) + EPSF)) / (n + EPSF);
    out[base] = s * factor;
}

// ---------------------------------------------------------------------------
extern "C" void kernel_launch(void* const* d_in, const int* in_sizes, int n_in,
                              void* d_out, int out_size, void* d_ws, size_t ws_size,
                              hipStream_t stream) {
    const float* x    = (const float*)d_in[0];  // (B, J, I)
    const float* w    = (const float*)d_in[1];  // (K, J, I)
    const float* bias = (const float*)d_in[2];  // (K, J, 1)
    float* out = (float*)d_out;                 // (B, K, I)

    float* cw = (float*)d_ws;                   // K*J*B floats   (2 MB)
    float* sp = cw + (size_t)K * J * B;         // 4*B*K*I floats (2 MB)

    hipLaunchKernelGGL(k1_craw,   dim3(B * J / 4), dim3(256), 0, stream, x, w, cw);
    hipLaunchKernelGGL(k2_softmax, dim3(K * J / 4), dim3(256), 0, stream, cw, bias);
    hipLaunchKernelGGL(k3_wsum,   dim3(512),       dim3(256), 0, stream, x, w, cw, sp);
    hipLaunchKernelGGL(k4_squash, dim3(B * K),     dim3(128), 0, stream, sp, out);
}

// Round 2
// 34.597 us; speedup vs baseline: 2.6700x; 2.6700x over previous
//
#include <hip/hip_runtime.h>
#include <math.h>

#define B 64
#define K 16
#define J 512
#define I 128
#define SCALE 0.08838834764831845f /* 1/sqrt(128) */
#define EPSF 1e-20f

// ---------------------------------------------------------------------------
// K1: fused logits + softmax-over-batch + bias.
// One block per j. Stage x^2 (64x128) and w^2 (16x128) in LDS with per-row
// rotation so the uniform-i inner loop is bank-conflict-free. Each thread
// owns a 2b x 2k tile of c_raw[k,b]; the batch-softmax is done with 10
// shfl_xor ops (b spans the 32 bp-lanes x 2 regs). Writes final c[k][j][b].
// ---------------------------------------------------------------------------
__global__ __launch_bounds__(256) void k1_craw_softmax(
    const float* __restrict__ x, const float* __restrict__ w,
    const float* __restrict__ bias, float* __restrict__ cw) {
    __shared__ float lx[64 * 128];  // x^2, row b rotated by b
    __shared__ float lw[16 * 128];  // w^2, row k rotated by k

    const int j = blockIdx.x;
    const int t = threadIdx.x;
    const int quad = t & 31;   // i-quad
    const int row = t >> 5;    // 0..7

#pragma unroll
    for (int rep = 0; rep < 8; ++rep) {
        int b = row + rep * 8;
        float4 v = *(const float4*)(x + ((size_t)b * J + j) * I + quad * 4);
        int ib = quad * 4;
        lx[b * 128 + ((ib + 0 + b) & 127)] = v.x * v.x;
        lx[b * 128 + ((ib + 1 + b) & 127)] = v.y * v.y;
        lx[b * 128 + ((ib + 2 + b) & 127)] = v.z * v.z;
        lx[b * 128 + ((ib + 3 + b) & 127)] = v.w * v.w;
    }
#pragma unroll
    for (int rep = 0; rep < 2; ++rep) {
        int k = row + rep * 8;
        float4 v = *(const float4*)(w + ((size_t)k * J + j) * I + quad * 4);
        int ib = quad * 4;
        lw[k * 128 + ((ib + 0 + k) & 127)] = v.x * v.x;
        lw[k * 128 + ((ib + 1 + k) & 127)] = v.y * v.y;
        lw[k * 128 + ((ib + 2 + k) & 127)] = v.z * v.z;
        lw[k * 128 + ((ib + 3 + k) & 127)] = v.w * v.w;
    }
    __syncthreads();

    const int bp = t & 31, kp = t >> 5;
    const int b0 = bp * 2, k0 = kp * 2;
    const float* px0 = lx + b0 * 128;
    const float* px1 = lx + (b0 + 1) * 128;
    const float* pw0 = lw + k0 * 128;
    const float* pw1 = lw + (k0 + 1) * 128;

    float a00 = 0.f, a01 = 0.f, a10 = 0.f, a11 = 0.f;
#pragma unroll 4
    for (int i = 0; i < 128; ++i) {
        float xa = px0[(i + b0) & 127];
        float xb = px1[(i + b0 + 1) & 127];
        float wa = pw0[(i + k0) & 127];
        float wb = pw1[(i + k0 + 1) & 127];
        a00 = fmaf(xa, wa, a00);
        a01 = fmaf(xa, wb, a01);
        a10 = fmaf(xb, wa, a10);
        a11 = fmaf(xb, wb, a11);
    }
    a00 *= SCALE; a01 *= SCALE; a10 *= SCALE; a11 *= SCALE;

    // softmax over batch: k0 column holds (a00,a10), k0+1 holds (a01,a11)
    float m0 = fmaxf(a00, a10), m1 = fmaxf(a01, a11);
#pragma unroll
    for (int s = 16; s >= 1; s >>= 1) {
        m0 = fmaxf(m0, __shfl_xor(m0, s, 64));
        m1 = fmaxf(m1, __shfl_xor(m1, s, 64));
    }
    float e00 = expf(a00 - m0), e10 = expf(a10 - m0);
    float e01 = expf(a01 - m1), e11 = expf(a11 - m1);
    float s0 = e00 + e10, s1 = e01 + e11;
#pragma unroll
    for (int s = 16; s >= 1; s >>= 1) {
        s0 += __shfl_xor(s0, s, 64);
        s1 += __shfl_xor(s1, s, 64);
    }
    float bias0 = bias[k0 * J + j];
    float bias1 = bias[(k0 + 1) * J + j];
    float2 c0 = make_float2(e00 / s0 + bias0, e10 / s0 + bias0);
    float2 c1 = make_float2(e01 / s1 + bias1, e11 / s1 + bias1);
    *(float2*)(cw + ((size_t)k0 * J + j) * B + b0) = c0;
    *(float2*)(cw + ((size_t)(k0 + 1) * J + j) * B + b0) = c1;
}

// ---------------------------------------------------------------------------
// K3: sp[jh][b][k][i] = sum_{j in chunk jh} x[b,j,i]*w[k,j,i]*c[k,j,b]
// Grid: 16 b-tiles x 4 k-tiles x jc chunks, XCD-swizzled so each XCD's
// x/w slice fits its private L2. Thread: 4b x 4k x float4 register tile.
// c staged in LDS (broadcast reads). Cross-jslice reduce via LDS, 2 rounds.
// ---------------------------------------------------------------------------
__global__ __launch_bounds__(256) void k3_wsum(
    const float* __restrict__ x, const float* __restrict__ w,
    const float* __restrict__ cw, float* __restrict__ sp, int Jc) {
    __shared__ float cl[128 * 16];       // [jj][kk][bb], max Jc=128
    __shared__ float red[256 * 36];      // [js*32+iq] rows, 8 float4 + pad

    const int nwg = gridDim.x;           // 64*jc, divisible by 8
    const int raw = blockIdx.x;
    const int cpx = nwg >> 3;
    const int swz = (raw & 7) * cpx + (raw >> 3);
    const int kt = swz & 3;
    const int bt = (swz >> 2) & 15;
    const int jh = swz >> 6;
    const int j0 = jh * Jc;
    const int b0 = bt * 4, k0 = kt * 4;

    const int iq = threadIdx.x & 31;
    const int js = threadIdx.x >> 5;

    for (int idx = threadIdx.x; idx < Jc * 16; idx += 256) {
        int jj = idx >> 4, kk = (idx >> 2) & 3, bb = idx & 3;
        cl[idx] = cw[((size_t)(k0 + kk) * J + j0 + jj) * B + b0 + bb];
    }
    __syncthreads();

    float4 acc[4][4];
#pragma unroll
    for (int bb = 0; bb < 4; ++bb)
#pragma unroll
        for (int kk = 0; kk < 4; ++kk) acc[bb][kk] = make_float4(0.f, 0.f, 0.f, 0.f);

    for (int j = j0 + js; j < j0 + Jc; j += 8) {
        float4 xv[4], wv[4];
#pragma unroll
        for (int bb = 0; bb < 4; ++bb)
            xv[bb] = *(const float4*)(x + ((size_t)(b0 + bb) * J + j) * I + iq * 4);
#pragma unroll
        for (int kk = 0; kk < 4; ++kk)
            wv[kk] = *(const float4*)(w + ((size_t)(k0 + kk) * J + j) * I + iq * 4);
        const float* cj = cl + (j - j0) * 16;
#pragma unroll
        for (int kk = 0; kk < 4; ++kk) {
#pragma unroll
            for (int bb = 0; bb < 4; ++bb) {
                float c = cj[kk * 4 + bb];
                acc[bb][kk].x = fmaf(xv[bb].x * wv[kk].x, c, acc[bb][kk].x);
                acc[bb][kk].y = fmaf(xv[bb].y * wv[kk].y, c, acc[bb][kk].y);
                acc[bb][kk].z = fmaf(xv[bb].z * wv[kk].z, c, acc[bb][kk].z);
                acc[bb][kk].w = fmaf(xv[bb].w * wv[kk].w, c, acc[bb][kk].w);
            }
        }
    }

    // cross-jslice reduction, 2 rounds of 8 slots (slot = bb*4+kk)
#pragma unroll
    for (int r = 0; r < 2; ++r) {
        __syncthreads();
#pragma unroll
        for (int s = 0; s < 8; ++s) {
            int slot = r * 8 + s;
            int bb = slot >> 2, kk = slot & 3;
            *(float4*)(red + (js * 32 + iq) * 36 + s * 4) = acc[bb][kk];
        }
        __syncthreads();
        int iq2 = threadIdx.x & 31, s2 = threadIdx.x >> 5;
        float4 v = make_float4(0.f, 0.f, 0.f, 0.f);
#pragma unroll
        for (int jss = 0; jss < 8; ++jss) {
            float4 u = *(const float4*)(red + (jss * 32 + iq2) * 36 + s2 * 4);
            v.x += u.x; v.y += u.y; v.z += u.z; v.w += u.w;
        }
        int slot = r * 8 + s2;
        int bb = slot >> 2, kk = slot & 3;
        *(float4*)(sp + (((size_t)jh * B + b0 + bb) * K + k0 + kk) * I + iq2 * 4) = v;
    }
}

// ---------------------------------------------------------------------------
// K4: sum nparts partials, squash over i, write out[b,k,i].
// ---------------------------------------------------------------------------
__global__ __launch_bounds__(128) void k4_squash(const float* __restrict__ sp,
                                                 float* __restrict__ out, int nparts) {
    const int bk = blockIdx.x;
    const int i = threadIdx.x;
    const size_t stride = (size_t)B * K * I;
    const size_t base = (size_t)bk * I + i;

    float s = 0.f;
    for (int p = 0; p < nparts; ++p) s += sp[base + p * stride];

    float q = s * s;
#pragma unroll
    for (int m = 32; m >= 1; m >>= 1) q += __shfl_xor(q, m, 64);
    __shared__ float red2[2];
    if ((threadIdx.x & 63) == 0) red2[threadIdx.x >> 6] = q;
    __syncthreads();
    float nsq = red2[0] + red2[1];

    float n = sqrtf(nsq);
    float factor = (1.0f - 1.0f / (expf(n) + EPSF)) / (n + EPSF);
    out[base] = s * factor;
}

// ---------------------------------------------------------------------------
extern "C" void kernel_launch(void* const* d_in, const int* in_sizes, int n_in,
                              void* d_out, int out_size, void* d_ws, size_t ws_size,
                              hipStream_t stream) {
    const float* x    = (const float*)d_in[0];  // (B, J, I)
    const float* w    = (const float*)d_in[1];  // (K, J, I)
    const float* bias = (const float*)d_in[2];  // (K, J, 1)
    float* out = (float*)d_out;                 // (B, K, I)

    const size_t cwf   = (size_t)K * J * B;     // 524288 floats (2 MB)
    const size_t partf = (size_t)B * K * I;     // 131072 floats (512 KB)

    int jc = 16;                                // partial count (j-chunks)
    if (ws_size < (cwf + 16 * partf) * 4) jc = 8;
    if (ws_size < (cwf + 8 * partf) * 4)  jc = 4;
    const int Jc = J / jc;

    float* cw = (float*)d_ws;
    float* sp = cw + cwf;

    hipLaunchKernelGGL(k1_craw_softmax, dim3(J), dim3(256), 0, stream, x, w, bias, cw);
    hipLaunchKernelGGL(k3_wsum, dim3(64 * jc), dim3(256), 0, stream, x, w, cw, sp, Jc);
    hipLaunchKernelGGL(k4_squash, dim3(B * K), dim3(128), 0, stream, sp, out, jc);
}

// Round 3
// 29.840 us; speedup vs baseline: 3.0956x; 1.1594x over previous
//
#include <hip/hip_runtime.h>
#include <math.h>

#define B 64
#define K 16
#define J 512
#define I 128
#define SCALE 0.08838834764831845f /* 1/sqrt(128) */
#define EPSF 1e-20f

typedef __attribute__((ext_vector_type(8))) short short8;
typedef __attribute__((ext_vector_type(4))) float f32x4;

static __device__ __forceinline__ unsigned f2bf(float f) {
    union { float f; unsigned u; } v; v.f = f;
    return (v.u + 0x7FFFu + ((v.u >> 16) & 1u)) >> 16;  // RNE truncate to bf16
}

// ---------------------------------------------------------------------------
// K1: fused logits (bf16 MFMA) + softmax-over-batch + bias -> cw[k][j][b].
// One wave per j. A = w^2 (16x128), B = x^2 (64 rows x 128, [n][k] storage).
// LDS tiles bf16 row-major, XOR-swizzled (byte ^= (row&7)<<4) so the
// fragment ds_read_b128 (16 lanes, same col, 256B row stride) is conflict-
// free. 16 MFMA per j; softmax fully in-register (8 shfl_xor per k-row).
// ---------------------------------------------------------------------------
__global__ __launch_bounds__(64) void k1_mfma(const float* __restrict__ x,
                                              const float* __restrict__ w,
                                              const float* __restrict__ bias,
                                              float* __restrict__ cw) {
    __shared__ __align__(16) char lx[64 * 256];  // x^2 bf16 [b][i]
    __shared__ __align__(16) char lw[16 * 256];  // w^2 bf16 [k][i]

    const int j = blockIdx.x;
    const int l = threadIdx.x;
    const int q = l & 31, hi = l >> 5;

    const float4* xs = (const float4*)x;
    const float4* wsrc = (const float4*)w;

#pragma unroll
    for (int it = 0; it < 32; ++it) {
        int b = it * 2 + hi;
        float4 v = xs[((size_t)b * J + j) * 32 + q];
        uint2 u;
        u.x = f2bf(v.x * v.x) | (f2bf(v.y * v.y) << 16);
        u.y = f2bf(v.z * v.z) | (f2bf(v.w * v.w) << 16);
        *(uint2*)(lx + b * 256 + ((q * 8) ^ ((b & 7) << 4))) = u;
    }
#pragma unroll
    for (int it = 0; it < 8; ++it) {
        int k = it * 2 + hi;
        float4 v = wsrc[((size_t)k * J + j) * 32 + q];
        uint2 u;
        u.x = f2bf(v.x * v.x) | (f2bf(v.y * v.y) << 16);
        u.y = f2bf(v.z * v.z) | (f2bf(v.w * v.w) << 16);
        *(uint2*)(lw + k * 256 + ((q * 8) ^ ((k & 7) << 4))) = u;
    }
    __syncthreads();

    const int g = l >> 4, n = l & 15;
    f32x4 acc[4];
#pragma unroll
    for (int t = 0; t < 4; ++t) acc[t] = (f32x4){0.f, 0.f, 0.f, 0.f};

#pragma unroll
    for (int s = 0; s < 4; ++s) {
        const int colb = s * 64 + g * 16;
        short8 af = *(const short8*)(lw + n * 256 + (colb ^ ((n & 7) << 4)));
#pragma unroll
        for (int t = 0; t < 4; ++t) {
            int row = t * 16 + n;
            short8 bf = *(const short8*)(lx + row * 256 + (colb ^ ((row & 7) << 4)));
            acc[t] = __builtin_amdgcn_mfma_f32_16x16x32_bf16(af, bf, acc[t], 0, 0, 0);
        }
    }

    // lane holds c_raw[m = g*4+r][b = t*16+n] in acc[t][r]
    float sc[4][4];
#pragma unroll
    for (int t = 0; t < 4; ++t)
#pragma unroll
        for (int r = 0; r < 4; ++r) sc[t][r] = acc[t][r] * SCALE;

#pragma unroll
    for (int r = 0; r < 4; ++r) {
        float mx = fmaxf(fmaxf(sc[0][r], sc[1][r]), fmaxf(sc[2][r], sc[3][r]));
#pragma unroll
        for (int msk = 1; msk <= 8; msk <<= 1) mx = fmaxf(mx, __shfl_xor(mx, msk, 64));
        float e0 = expf(sc[0][r] - mx), e1 = expf(sc[1][r] - mx);
        float e2 = expf(sc[2][r] - mx), e3 = expf(sc[3][r] - mx);
        float sum = e0 + e1 + e2 + e3;
#pragma unroll
        for (int msk = 1; msk <= 8; msk <<= 1) sum += __shfl_xor(sum, msk, 64);
        float inv = 1.f / sum;
        int m = g * 4 + r;
        float bi = bias[m * J + j];
        size_t base = ((size_t)m * J + j) * B + n;
        cw[base]      = e0 * inv + bi;
        cw[base + 16] = e1 * inv + bi;
        cw[base + 32] = e2 * inv + bi;
        cw[base + 48] = e3 * inv + bi;
    }
}

// ---------------------------------------------------------------------------
// K3: sp[jh][b][k][i] = sum_{j in chunk jh} x[b,j,i]*w[k,j,i]*c[k,j,b]
// Grid: 16 b-tiles x 4 k-tiles x jc chunks, XCD-swizzled. Thread: 4b x 4k x
// float4 register tile; c staged in LDS; cross-jslice reduce via LDS.
// ---------------------------------------------------------------------------
__global__ __launch_bounds__(256) void k3_wsum(
    const float* __restrict__ x, const float* __restrict__ w,
    const float* __restrict__ cw, float* __restrict__ sp, int Jc) {
    __shared__ float cl[128 * 16];       // [jj][kk][bb], max Jc=128
    __shared__ float red[256 * 36];      // [js*32+iq] rows, 8 float4 + pad

    const int nwg = gridDim.x;           // 64*jc, divisible by 8
    const int raw = blockIdx.x;
    const int cpx = nwg >> 3;
    const int swz = (raw & 7) * cpx + (raw >> 3);
    const int kt = swz & 3;
    const int bt = (swz >> 2) & 15;
    const int jh = swz >> 6;
    const int j0 = jh * Jc;
    const int b0 = bt * 4, k0 = kt * 4;

    const int iq = threadIdx.x & 31;
    const int js = threadIdx.x >> 5;

    for (int idx = threadIdx.x; idx < Jc * 16; idx += 256) {
        int jj = idx >> 4, kk = (idx >> 2) & 3, bb = idx & 3;
        cl[idx] = cw[((size_t)(k0 + kk) * J + j0 + jj) * B + b0 + bb];
    }
    __syncthreads();

    float4 acc[4][4];
#pragma unroll
    for (int bb = 0; bb < 4; ++bb)
#pragma unroll
        for (int kk = 0; kk < 4; ++kk) acc[bb][kk] = make_float4(0.f, 0.f, 0.f, 0.f);

    for (int j = j0 + js; j < j0 + Jc; j += 8) {
        float4 xv[4], wv[4];
#pragma unroll
        for (int bb = 0; bb < 4; ++bb)
            xv[bb] = *(const float4*)(x + ((size_t)(b0 + bb) * J + j) * I + iq * 4);
#pragma unroll
        for (int kk = 0; kk < 4; ++kk)
            wv[kk] = *(const float4*)(w + ((size_t)(k0 + kk) * J + j) * I + iq * 4);
        const float* cj = cl + (j - j0) * 16;
#pragma unroll
        for (int kk = 0; kk < 4; ++kk) {
#pragma unroll
            for (int bb = 0; bb < 4; ++bb) {
                float c = cj[kk * 4 + bb];
                acc[bb][kk].x = fmaf(xv[bb].x * wv[kk].x, c, acc[bb][kk].x);
                acc[bb][kk].y = fmaf(xv[bb].y * wv[kk].y, c, acc[bb][kk].y);
                acc[bb][kk].z = fmaf(xv[bb].z * wv[kk].z, c, acc[bb][kk].z);
                acc[bb][kk].w = fmaf(xv[bb].w * wv[kk].w, c, acc[bb][kk].w);
            }
        }
    }

#pragma unroll
    for (int r = 0; r < 2; ++r) {
        __syncthreads();
#pragma unroll
        for (int s = 0; s < 8; ++s) {
            int slot = r * 8 + s;
            int bb = slot >> 2, kk = slot & 3;
            *(float4*)(red + (js * 32 + iq) * 36 + s * 4) = acc[bb][kk];
        }
        __syncthreads();
        int iq2 = threadIdx.x & 31, s2 = threadIdx.x >> 5;
        float4 v = make_float4(0.f, 0.f, 0.f, 0.f);
#pragma unroll
        for (int jss = 0; jss < 8; ++jss) {
            float4 u = *(const float4*)(red + (jss * 32 + iq2) * 36 + s2 * 4);
            v.x += u.x; v.y += u.y; v.z += u.z; v.w += u.w;
        }
        int slot = r * 8 + s2;
        int bb = slot >> 2, kk = slot & 3;
        *(float4*)(sp + (((size_t)jh * B + b0 + bb) * K + k0 + kk) * I + iq2 * 4) = v;
    }
}

// ---------------------------------------------------------------------------
// K4: sum nparts partials, squash over i, write out[b,k,i].
// ---------------------------------------------------------------------------
__global__ __launch_bounds__(128) void k4_squash(const float* __restrict__ sp,
                                                 float* __restrict__ out, int nparts) {
    const int bk = blockIdx.x;
    const int i = threadIdx.x;
    const size_t stride = (size_t)B * K * I;
    const size_t base = (size_t)bk * I + i;

    float s = 0.f;
    for (int p = 0; p < nparts; ++p) s += sp[base + p * stride];

    float q = s * s;
#pragma unroll
    for (int m = 32; m >= 1; m >>= 1) q += __shfl_xor(q, m, 64);
    __shared__ float red2[2];
    if ((threadIdx.x & 63) == 0) red2[threadIdx.x >> 6] = q;
    __syncthreads();
    float nsq = red2[0] + red2[1];

    float n = sqrtf(nsq);
    float factor = (1.0f - 1.0f / (expf(n) + EPSF)) / (n + EPSF);
    out[base] = s * factor;
}

// ---------------------------------------------------------------------------
extern "C" void kernel_launch(void* const* d_in, const int* in_sizes, int n_in,
                              void* d_out, int out_size, void* d_ws, size_t ws_size,
                              hipStream_t stream) {
    const float* x    = (const float*)d_in[0];  // (B, J, I)
    const float* w    = (const float*)d_in[1];  // (K, J, I)
    const float* bias = (const float*)d_in[2];  // (K, J, 1)
    float* out = (float*)d_out;                 // (B, K, I)

    const size_t cwf   = (size_t)K * J * B;     // 524288 floats (2 MB)
    const size_t partf = (size_t)B * K * I;     // 131072 floats (512 KB)

    int jc = 16;                                // partial count (j-chunks)
    if (ws_size < (cwf + 16 * partf) * 4) jc = 8;
    if (ws_size < (cwf + 8 * partf) * 4)  jc = 4;
    const int Jc = J / jc;

    float* cw = (float*)d_ws;
    float* sp = cw + cwf;

    hipLaunchKernelGGL(k1_mfma,  dim3(J),       dim3(64),  0, stream, x, w, bias, cw);
    hipLaunchKernelGGL(k3_wsum,  dim3(64 * jc), dim3(256), 0, stream, x, w, cw, sp, Jc);
    hipLaunchKernelGGL(k4_squash, dim3(B * K),  dim3(128), 0, stream, sp, out, jc);
}